// Round 1
// baseline (186.245 us; speedup 1.0000x reference)
//
#include <hip/hip_runtime.h>
#include <hip/hip_fp16.h>

#define EPS 1e-5f

constexpr int B = 8;
constexpr int V = 100000;
constexpr int F = 200000;
constexpr int U = 1024;
constexpr int T = 110000;
constexpr int CAP = 24;                     // max faces/vertex (data max ~20)

constexpr int NBUK = (V + 127) / 128;       // 782 buckets, 128 vertices each
constexpr int N4   = (3 * F) / 4;           // 150000 int4 edge-quads
constexpr int EB   = (N4 + 255) / 256;      // 586 edge blocks
constexpr int TRB  = (V + 255) / 256;       // 391 transpose blocks

constexpr int FQ   = 8;                     // faces per thread (FN role ILP)
constexpr int FNB  = (F * 8 / FQ + 255) / 256;   // 782 blocks
constexpr int TQ   = 4;                     // samples per thread (corner role)
constexpr int CPB  = (T / TQ + 255) / 256;       // 108 blocks
constexpr int SQ   = 2;                     // samples per thread (k6)
constexpr int VQ   = 2;                     // vertices per thread (k7)

// packed half4 (8 B): x,y,z in halves, w pad
struct alignas(8) h4 { __half2 a, b; };
__device__ inline h4 pack_h4(float x, float y, float z) {
    h4 r; r.a = __floats2half2_rn(x, y); r.b = __floats2half2_rn(z, 0.0f);
    return r;
}
__device__ inline float3 unpack_h4(h4 v) {
    float2 xy = __half22float2(v.a);
    float2 zw = __half22float2(v.b);
    return make_float3(xy.x, xy.y, zw.x);
}

// 16 B corner record: 3x21-bit indices packed in (lo,hi) + half weights
struct alignas(16) Corner16 { unsigned lo, hi; __half2 w01; __half2 w2_; };
__device__ inline Corner16 pack_corner(int i0, int i1, int i2,
                                       float w0, float w1, float w2) {
    unsigned long long x = (unsigned long long)(unsigned)i0
                         | ((unsigned long long)(unsigned)i1 << 21)
                         | ((unsigned long long)(unsigned)i2 << 42);
    Corner16 c;
    c.lo = (unsigned)x;
    c.hi = (unsigned)(x >> 32);
    c.w01 = __floats2half2_rn(w0, w1);
    c.w2_ = __floats2half2_rn(w2, 0.0f);
    return c;
}

// ---------------------------------------------------------------------------
// K1: three independent roles (none depend on each other's output):
//   [0, TRB):           transpose verts -> (V,8) packed float3 rows (fp32!
//                       positions must NOT be quantized before the cross
//                       product). 96 B/vertex contiguous, written as 6 float4.
//   [TRB, TRB+EB):      per-block bucket histogram (LDS) -> atomicAdd tot[b].
//                       (replaces the old (EB,NBUK) hist matrix + transposed
//                       scan, which cost ~29 MB of 64B-line amplification)
//   [TRB+EB, +CPB):     corner precompute (moved here from k2 to balance the
//                       two fat kernels; it has no deps on k1 outputs)
// ---------------------------------------------------------------------------
__global__ void k1_pre(const float* __restrict__ verts,
                       float* __restrict__ vertsT,           // (V,8) float3
                       const int* __restrict__ vi,
                       int* __restrict__ tot,                // (NBUK), pre-zeroed
                       const int* __restrict__ index_image,  // (U,U,3)
                       const float* __restrict__ bary_image, // (U,U,3)
                       const float* __restrict__ vt,         // (T,2)
                       Corner16* __restrict__ corners) {     // (T,4)
    __shared__ int lh[NBUK];
    int blk = blockIdx.x;

    if (blk < TRB) {
        int v = blk * 256 + threadIdx.x;
        if (v >= V) return;
        float buf[24];
#pragma unroll
        for (int b = 0; b < 8; ++b) {
            const float* p = verts + (size_t)b * V * 3 + (size_t)v * 3;
            buf[b * 3 + 0] = p[0];
            buf[b * 3 + 1] = p[1];
            buf[b * 3 + 2] = p[2];
        }
        float4* dst = (float4*)(vertsT + (size_t)v * 24);
#pragma unroll
        for (int i = 0; i < 6; ++i)
            dst[i] = make_float4(buf[4 * i], buf[4 * i + 1],
                                 buf[4 * i + 2], buf[4 * i + 3]);
        return;
    }

    if (blk < TRB + EB) {
        int k = blk - TRB;
        for (int i = threadIdx.x; i < NBUK; i += 256) lh[i] = 0;
        __syncthreads();
        int m4 = k * 256 + threadIdx.x;
        if (m4 < N4) {
            int4 e = ((const int4*)vi)[m4];
            atomicAdd(&lh[e.x >> 7], 1);
            atomicAdd(&lh[e.y >> 7], 1);
            atomicAdd(&lh[e.z >> 7], 1);
            atomicAdd(&lh[e.w >> 7], 1);
        }
        __syncthreads();
        for (int b = threadIdx.x; b < NBUK; b += 256)
            if (lh[b]) atomicAdd(&tot[b], lh[b]);
        return;
    }

    // --- corner precompute, TQ=4 samples per thread ---
    int tbase = (blk - TRB - EB) * 256 + threadIdx.x;
    if (tbase >= T / TQ) return;
#pragma unroll
    for (int qq = 0; qq < TQ; ++qq) {
        int t = tbase + qq * (T / TQ);

        float gx = vt[t * 2 + 0];
        float gy = vt[t * 2 + 1];
        float ix = gx * (float)U - 0.5f;
        float iy = gy * (float)U - 0.5f;

        float x0f = floorf(ix);
        float y0f = floorf(iy);
        int x0 = (int)x0f;
        int y0 = (int)y0f;
        float wx1 = ix - x0f, wx0 = 1.0f - wx1;
        float wy1 = iy - y0f, wy0 = 1.0f - wy1;

#pragma unroll
        for (int c = 0; c < 4; ++c) {
            int cy = c >> 1, cx = c & 1;
            int y = y0 + cy;
            int x = x0 + cx;
            int i0 = 0, i1 = 0, i2 = 0;
            float w0 = 0.0f, w1 = 0.0f, w2 = 0.0f;
            if (x >= 0 && x < U && y >= 0 && y < U) {
                float w = (cy ? wy1 : wy0) * (cx ? wx1 : wx0);
                int pix = y * U + x;
                int j0 = index_image[pix * 3 + 0];
                int j1 = index_image[pix * 3 + 1];
                int j2 = index_image[pix * 3 + 2];
                float m = (j0 != -1 && j1 != -1 && j2 != -1) ? 1.0f : 0.0f;
                float wm = w * m;
                i0 = min(max(j0, 0), V - 1);
                i1 = min(max(j1, 0), V - 1);
                i2 = min(max(j2, 0), V - 1);
                w0 = wm * bary_image[pix * 3 + 0];
                w1 = wm * bary_image[pix * 3 + 1];
                w2 = wm * bary_image[pix * 3 + 2];
            }
            corners[t * 4 + c] = pack_corner(i0, i1, i2, w0, w1, w2);
        }
    }
}

// Redundant per-block exclusive scan of tot -> pre[0..NBUK] in LDS.
// MUST be called by ALL threads of a 256-thread block (contains barriers).
__device__ inline void scan_base(const int* __restrict__ tot,
                                 int* pre, int* part) {
    constexpr int CH = (NBUK + 255) / 256;  // 4
    int th = threadIdx.x;
    int loc[CH];
    int local = 0;
#pragma unroll
    for (int j = 0; j < CH; ++j) {
        int idx = th * CH + j;
        int c = (idx < NBUK) ? tot[idx] : 0;
        loc[j] = local;           // exclusive within chunk
        local += c;
    }
    part[th] = local;
    __syncthreads();
    for (int off = 1; off < 256; off <<= 1) {
        int x = (th >= off) ? part[th - off] : 0;
        __syncthreads();
        part[th] += x;
        __syncthreads();
    }
    int excl = part[th] - local;
#pragma unroll
    for (int j = 0; j < CH; ++j) {
        int idx = th * CH + j;
        if (idx < NBUK) pre[idx] = excl + loc[j];
    }
    if (th == 255) pre[NBUK] = part[255];
    __syncthreads();
}

// ---------------------------------------------------------------------------
// K2: two roles:
//   [0, FNB):        face normals, FQ=8 faces per thread, float3 gathers
//                    (24 x 12 B in flight per lane), fp16 out.
//                    __launch_bounds__(256,2) raises the register budget so
//                    the gathers actually stay in flight (old VGPR=40 proved
//                    the compiler was serializing them).
//   [FNB, FNB+EB):   scatter edges to bucket regions. Intra-bucket order is
//                    irrelevant (k5 sums), so positions come from LDS ranks +
//                    one global atomicAdd per (block,bucket) on cursor[].
// ---------------------------------------------------------------------------
__global__ __launch_bounds__(256, 2) void k2_fused(
        const int* __restrict__ vi,          // (F,3) flat
        const float* __restrict__ vertsT,    // (V,8) float3
        h4* __restrict__ fn,                 // (F,8)
        const int* __restrict__ tot,         // (NBUK)
        int* __restrict__ cursor,            // (NBUK), pre-zeroed
        int* __restrict__ pairs) {           // (3F)
    int blk = blockIdx.x;

    if (blk < FNB) {
        int id = blk * 256 + threadIdx.x;
        if (id >= F * 8 / FQ) return;
        int b = id & 7;
        int fbase = id >> 3;                 // [0, F/FQ)
        const float3* vT = (const float3*)vertsT;

        int ia[FQ], ib[FQ], ic[FQ];
        float3 p0[FQ], p1[FQ], p2[FQ];
#pragma unroll
        for (int q = 0; q < FQ; ++q) {
            int f = fbase + q * (F / FQ);
            ia[q] = vi[f * 3 + 0];
            ib[q] = vi[f * 3 + 1];
            ic[q] = vi[f * 3 + 2];
        }
#pragma unroll
        for (int q = 0; q < FQ; ++q) {
            p0[q] = vT[(size_t)ia[q] * 8 + b];
            p1[q] = vT[(size_t)ib[q] * 8 + b];
            p2[q] = vT[(size_t)ic[q] * 8 + b];
        }
#pragma unroll
        for (int q = 0; q < FQ; ++q) {
            int f = fbase + q * (F / FQ);
            float e1x = p1[q].x - p0[q].x, e1y = p1[q].y - p0[q].y, e1z = p1[q].z - p0[q].z;
            float e2x = p2[q].x - p0[q].x, e2y = p2[q].y - p0[q].y, e2z = p2[q].z - p0[q].z;

            float nx = e1y * e2z - e1z * e2y;
            float ny = e1z * e2x - e1x * e2z;
            float nz = e1x * e2y - e1y * e2x;

            float norm = sqrtf(nx * nx + ny * ny + nz * nz);
            float inv = (norm < EPS) ? 1.0f : (1.0f / norm);
            fn[(size_t)f * 8 + b] = pack_h4(nx * inv, ny * inv, nz * inv);
        }
        return;
    }

    // --- scatter role (ex-k4): no hist matrix, no transposed scan ---
    __shared__ int pre[NBUK + 1];
    __shared__ int part[256];
    __shared__ int lh[NBUK];
    __shared__ int base[NBUK];
    scan_base(tot, pre, part);
    for (int i = threadIdx.x; i < NBUK; i += 256) lh[i] = 0;
    __syncthreads();

    int k = blk - FNB;
    int m4 = k * 256 + threadIdx.x;
    bool act = (m4 < N4);
    int vv[4], rr[4], bbk[4], fc[4];
    if (act) {
        int4 e = ((const int4*)vi)[m4];
        vv[0] = e.x; vv[1] = e.y; vv[2] = e.z; vv[3] = e.w;
        int be = m4 * 4;
#pragma unroll
        for (int j = 0; j < 4; ++j) {
            bbk[j] = vv[j] >> 7;
            rr[j] = atomicAdd(&lh[bbk[j]], 1);
            fc[j] = (be + j) / 3;
        }
    }
    __syncthreads();
    for (int i = threadIdx.x; i < NBUK; i += 256)
        base[i] = lh[i] ? atomicAdd(&cursor[i], lh[i]) : 0;
    __syncthreads();
    if (act) {
#pragma unroll
        for (int j = 0; j < 4; ++j) {
            int pos = pre[bbk[j]] + base[bbk[j]] + rr[j];
            pairs[pos] = ((vv[j] & 127) << 18) | fc[j];
        }
    }
}

// ---------------------------------------------------------------------------
// K5: per-bucket ELL build in LDS + fp16 fn gather + normalize -> fp16 vn.
// 256 threads (scan_base barrier-uniform). Gather loop unrolled x2 so two
// 64 B fn gathers are always in flight.
// ---------------------------------------------------------------------------
__global__ __launch_bounds__(256) void k5_gather(
        const int* __restrict__ pairs,
        const int* __restrict__ tot,
        const h4* __restrict__ fn,       // (F,8)
        h4* __restrict__ vn) {           // (V,8)
    __shared__ int cnt[128];
    __shared__ int rows[128 * CAP];      // 12.3 KB
    __shared__ int pre[NBUK + 1];
    __shared__ int part[256];
    scan_base(tot, pre, part);           // all 256 threads, uniform barriers

    int tid = threadIdx.x;
    if (tid < 128) cnt[tid] = 0;
    __syncthreads();

    int b = blockIdx.x;
    int start = pre[b], end = pre[b + 1];
    for (int i = start + tid; i < end; i += 256) {
        int pk = pairs[i];
        int vl = pk >> 18;
        int f = pk & 0x3FFFF;
        int pos = atomicAdd(&cnt[vl], 1);
        if (pos < CAP) rows[vl * CAP + pos] = f;
    }
    __syncthreads();

    int v0 = b << 7;
    for (int id = tid; id < 128 * 8; id += 256) {
        int vl = id >> 3, b8 = id & 7;
        int v = v0 + vl;
        if (v >= V) continue;
        int deg = min(cnt[vl], CAP);
        float ax = 0.0f, ay = 0.0f, az = 0.0f;
        int j = 0;
        for (; j + 1 < deg; j += 2) {
            h4 r0 = fn[(size_t)rows[vl * CAP + j] * 8 + b8];
            h4 r1 = fn[(size_t)rows[vl * CAP + j + 1] * 8 + b8];
            float3 n0 = unpack_h4(r0);
            float3 n1 = unpack_h4(r1);
            ax += n0.x + n1.x; ay += n0.y + n1.y; az += n0.z + n1.z;
        }
        if (j < deg) {
            float3 n = unpack_h4(fn[(size_t)rows[vl * CAP + j] * 8 + b8]);
            ax += n.x; ay += n.y; az += n.z;
        }
        float nn = sqrtf(ax * ax + ay * ay + az * az);
        float inv = (nn < EPS) ? 1.0f : (1.0f / nn);
        vn[(size_t)v * 8 + b8] = pack_h4(ax * inv, ay * inv, az * inv);
    }
}

// ---------------------------------------------------------------------------
// K6: sample with 16 B packed corners, SQ=2 samples per thread (24 vn
// gathers in flight). 8 lanes share each t -> corner loads broadcast.
// ---------------------------------------------------------------------------
__global__ void sample_points(const h4* __restrict__ vn,           // (V,8)
                              const Corner16* __restrict__ corners,// (T,4)
                              h4* __restrict__ vals) {             // (T,8)
    int id = blockIdx.x * blockDim.x + threadIdx.x;
    if (id >= (T / SQ) * 8) return;
    int b = id & 7;
    int tb = id >> 3;

#pragma unroll
    for (int s = 0; s < SQ; ++s) {
        int t = tb + s * (T / SQ);
        float ax = 0.0f, ay = 0.0f, az = 0.0f;
        Corner16 cr[4];
#pragma unroll
        for (int c = 0; c < 4; ++c) cr[c] = corners[t * 4 + c];
        h4 q[12];
#pragma unroll
        for (int c = 0; c < 4; ++c) {
            unsigned long long x = (unsigned long long)cr[c].lo
                                 | ((unsigned long long)cr[c].hi << 32);
            int i0 = (int)(x & 0x1FFFFF);
            int i1 = (int)((x >> 21) & 0x1FFFFF);
            int i2 = (int)(x >> 42);
            q[c * 3 + 0] = vn[(size_t)i0 * 8 + b];
            q[c * 3 + 1] = vn[(size_t)i1 * 8 + b];
            q[c * 3 + 2] = vn[(size_t)i2 * 8 + b];
        }
#pragma unroll
        for (int c = 0; c < 4; ++c) {
            float2 w01 = __half22float2(cr[c].w01);
            float w2 = __low2float(cr[c].w2_);
            float3 q0 = unpack_h4(q[c * 3 + 0]);
            float3 q1 = unpack_h4(q[c * 3 + 1]);
            float3 q2 = unpack_h4(q[c * 3 + 2]);
            ax += w01.x * q0.x + w01.y * q1.x + w2 * q2.x;
            ay += w01.x * q0.y + w01.y * q1.y + w2 * q2.y;
            az += w01.x * q0.z + w01.y * q1.z + w2 * q2.z;
        }
        vals[(size_t)t * 8 + b] = pack_h4(ax, ay, az);
    }
}

// ---------------------------------------------------------------------------
// K7: out[b,v,:] = mean over K=2 of vals[v2uv[v,k], b]. VQ=2 vertices per
// thread (4 gathers in flight). fp32 output.
// ---------------------------------------------------------------------------
__global__ void gather_out(const h4* __restrict__ vals,     // (T,8)
                           const int* __restrict__ v2uv,    // (V,2)
                           float* __restrict__ out) {       // (B,V,3)
    int id = blockIdx.x * blockDim.x + threadIdx.x;
    if (id >= (V / VQ) * 8) return;
    int b = id & 7;
    int vb = id >> 3;

    int t0[VQ], t1[VQ];
    h4 xa[VQ], ya[VQ];
#pragma unroll
    for (int s = 0; s < VQ; ++s) {
        int v = vb + s * (V / VQ);
        t0[s] = v2uv[v * 2 + 0];
        t1[s] = v2uv[v * 2 + 1];
    }
#pragma unroll
    for (int s = 0; s < VQ; ++s) {
        xa[s] = vals[(size_t)t0[s] * 8 + b];
        ya[s] = vals[(size_t)t1[s] * 8 + b];
    }
#pragma unroll
    for (int s = 0; s < VQ; ++s) {
        int v = vb + s * (V / VQ);
        float3 x = unpack_h4(xa[s]);
        float3 y = unpack_h4(ya[s]);
        float* o = out + (size_t)b * V * 3 + (size_t)v * 3;
        o[0] = 0.5f * (x.x + y.x);
        o[1] = 0.5f * (x.y + y.y);
        o[2] = 0.5f * (x.z + y.z);
    }
}

extern "C" void kernel_launch(void* const* d_in, const int* in_sizes, int n_in,
                              void* d_out, int out_size, void* d_ws, size_t ws_size,
                              hipStream_t stream) {
    const float* verts   = (const float*)d_in[0]; // (B,V,3)
    const float* bary    = (const float*)d_in[1]; // (U,U,3)
    const float* vt      = (const float*)d_in[2]; // (T,2)
    const int*   vi      = (const int*)d_in[3];   // (F,3)
    const int*   idx_img = (const int*)d_in[4];   // (U,U,3)
    const int*   v2uv    = (const int*)d_in[5];   // (V,2)
    float* out = (float*)d_out;

    // Workspace (~32 MB), aliased by stream-ordered disjoint lifetimes:
    //   region A (9.6 MB):  vertsT float3 (K1 w, K2 r) -> vn h4 6.4 MB (K5 w, K6 r)
    //   region B (12.8 MB): fn h4 (K2 w, K5 r) -> vals h4 7.04 MB (K6 w, K7 r)
    //   region C (7.04 MB): corners 16 B packed (K1 w, K6 r)
    //   region D: tot 3 KB, cursor 3 KB, pairs 2.4 MB
    float*    vertsT  = (float*)d_ws;                           // V*8 float3
    h4*       vn      = (h4*)d_ws;                              // alias
    h4*       fn      = (h4*)((char*)d_ws + (size_t)V * 8 * 12);
    h4*       vals    = fn;                                     // alias
    Corner16* corners = (Corner16*)((char*)fn + (size_t)F * 8 * sizeof(h4));
    int*      tot     = (int*)(corners + (size_t)T * 4);        // NBUK
    int*      cursor  = tot + NBUK;                             // NBUK
    int*      pairs   = cursor + NBUK;                          // 3F

    const int BLK = 256;
    hipMemsetAsync(tot, 0, 2 * NBUK * sizeof(int), stream);     // tot + cursor
    k1_pre<<<TRB + EB + CPB, BLK, 0, stream>>>(
        verts, vertsT, vi, tot, idx_img, bary, vt, corners);
    k2_fused<<<FNB + EB, BLK, 0, stream>>>(vi, vertsT, fn, tot, cursor, pairs);
    k5_gather<<<NBUK, BLK, 0, stream>>>(pairs, tot, fn, vn);
    sample_points<<<((T / SQ) * 8 + BLK - 1) / BLK, BLK, 0, stream>>>(
        vn, corners, vals);
    gather_out<<<((V / VQ) * 8 + BLK - 1) / BLK, BLK, 0, stream>>>(
        vals, v2uv, out);
}

// Round 2
// 181.437 us; speedup vs baseline: 1.0265x; 1.0265x over previous
//
#include <hip/hip_runtime.h>
#include <hip/hip_fp16.h>

#define EPS 1e-5f

constexpr int B = 8;
constexpr int V = 100000;
constexpr int F = 200000;
constexpr int U = 1024;
constexpr int T = 110000;
constexpr int CAP = 24;                     // max faces/vertex (data max ~20)

constexpr int NBUK = (V + 127) / 128;       // 782 buckets, 128 vertices each
constexpr int N4   = (3 * F) / 4;           // 150000 int4 edge-quads
constexpr int EB   = (N4 + 255) / 256;      // 586 edge blocks
constexpr int TRB  = (V + 255) / 256;       // 391 transpose blocks

constexpr int FQ   = 8;                     // faces per thread (FN role ILP)
constexpr int FNB  = (F * 8 / FQ + 255) / 256;   // 782 blocks
constexpr int TQ   = 4;                     // samples per thread (corner role)
constexpr int CPB  = (T / TQ + 255) / 256;       // 108 blocks
constexpr int SQ   = 2;                     // samples per thread (k6)
constexpr int VQ   = 2;                     // vertices per thread (k7)

// packed half4 (8 B): x,y,z in halves, w pad
struct alignas(8) h4 { __half2 a, b; };
__device__ inline h4 pack_h4(float x, float y, float z) {
    h4 r; r.a = __floats2half2_rn(x, y); r.b = __floats2half2_rn(z, 0.0f);
    return r;
}
__device__ inline float3 unpack_h4(h4 v) {
    float2 xy = __half22float2(v.a);
    float2 zw = __half22float2(v.b);
    return make_float3(xy.x, xy.y, zw.x);
}

// 16 B corner record: 3x21-bit indices packed in (lo,hi) + half weights
struct alignas(16) Corner16 { unsigned lo, hi; __half2 w01; __half2 w2_; };
__device__ inline Corner16 pack_corner(int i0, int i1, int i2,
                                       float w0, float w1, float w2) {
    unsigned long long x = (unsigned long long)(unsigned)i0
                         | ((unsigned long long)(unsigned)i1 << 21)
                         | ((unsigned long long)(unsigned)i2 << 42);
    Corner16 c;
    c.lo = (unsigned)x;
    c.hi = (unsigned)(x >> 32);
    c.w01 = __floats2half2_rn(w0, w1);
    c.w2_ = __floats2half2_rn(w2, 0.0f);
    return c;
}

// ---------------------------------------------------------------------------
// K1: two roles (lean serial predecessor — everything that can run
// concurrently with the FN gather lives in K2 instead):
//   [0, TRB):      transpose verts -> (V,8) float4 rows (fp32! positions must
//                  NOT be quantized before the cross product; 128 B/vertex,
//                  line-aligned so each (v,b) gather touches exactly 2 lines
//                  and compiles to a single dwordx4)
//   [TRB, TRB+EB): per-block bucket histogram (LDS) -> atomicAdd tot[b].
//                  (the old (EB,NBUK) hist matrix + transposed scan cost
//                  ~29 MB of 64B-line amplification — stays dead)
// ---------------------------------------------------------------------------
__global__ void k1_pre(const float* __restrict__ verts,
                       float4* __restrict__ vertsT,          // (V,8)
                       const int* __restrict__ vi,
                       int* __restrict__ tot) {              // (NBUK), zeroed
    __shared__ int lh[NBUK];
    int blk = blockIdx.x;

    if (blk < TRB) {
        int v = blk * 256 + threadIdx.x;
        if (v >= V) return;
        float4 row[8];
#pragma unroll
        for (int b = 0; b < 8; ++b) {
            const float* p = verts + (size_t)b * V * 3 + (size_t)v * 3;
            row[b] = make_float4(p[0], p[1], p[2], 0.0f);
        }
        float4* dst = vertsT + (size_t)v * 8;
#pragma unroll
        for (int b = 0; b < 8; ++b) dst[b] = row[b];
        return;
    }

    int k = blk - TRB;
    for (int i = threadIdx.x; i < NBUK; i += 256) lh[i] = 0;
    __syncthreads();
    int m4 = k * 256 + threadIdx.x;
    if (m4 < N4) {
        int4 e = ((const int4*)vi)[m4];
        atomicAdd(&lh[e.x >> 7], 1);
        atomicAdd(&lh[e.y >> 7], 1);
        atomicAdd(&lh[e.z >> 7], 1);
        atomicAdd(&lh[e.w >> 7], 1);
    }
    __syncthreads();
    for (int b = threadIdx.x; b < NBUK; b += 256)
        if (lh[b]) atomicAdd(&tot[b], lh[b]);
}

// Redundant per-block exclusive scan of tot -> pre[0..NBUK] in LDS.
// MUST be called by ALL threads of a 256-thread block (contains barriers).
__device__ inline void scan_base(const int* __restrict__ tot,
                                 int* pre, int* part) {
    constexpr int CH = (NBUK + 255) / 256;  // 4
    int th = threadIdx.x;
    int loc[CH];
    int local = 0;
#pragma unroll
    for (int j = 0; j < CH; ++j) {
        int idx = th * CH + j;
        int c = (idx < NBUK) ? tot[idx] : 0;
        loc[j] = local;           // exclusive within chunk
        local += c;
    }
    part[th] = local;
    __syncthreads();
    for (int off = 1; off < 256; off <<= 1) {
        int x = (th >= off) ? part[th - off] : 0;
        __syncthreads();
        part[th] += x;
        __syncthreads();
    }
    int excl = part[th] - local;
#pragma unroll
    for (int j = 0; j < CH; ++j) {
        int idx = th * CH + j;
        if (idx < NBUK) pre[idx] = excl + loc[j];
    }
    if (th == 255) pre[NBUK] = part[255];
    __syncthreads();
}

// ---------------------------------------------------------------------------
// K2: three concurrent roles, no launch_bounds override (round-1 post-mortem:
// the (256,2) cap halved occupancy on a gather-latency-bound kernel; VGPR=40
// + 8 blocks/CU TLP is the winning configuration, verified round 0):
//   [0, FNB):           face normals, FQ=8 faces per thread (24 float4
//                       gathers in flight per lane group), fp16 out
//   [FNB, FNB+CPB):     corner precompute, TQ=4 samples per thread
//                       (runs concurrently with FN blocks — keeps the tail
//                       of the grid busy while FN waits on gathers)
//   [FNB+CPB, +EB):     scatter edges to bucket regions. Intra-bucket order
//                       is irrelevant (k5 sums), so positions come from LDS
//                       ranks + one global atomicAdd per (block,bucket).
// ---------------------------------------------------------------------------
__global__ void k2_fused(const int* __restrict__ vi,          // (F,3) flat
                         const float4* __restrict__ vertsT,   // (V,8)
                         h4* __restrict__ fn,                 // (F,8)
                         const int* __restrict__ index_image, // (U,U,3)
                         const float* __restrict__ bary_image,// (U,U,3)
                         const float* __restrict__ vt,        // (T,2)
                         Corner16* __restrict__ corners,      // (T,4)
                         const int* __restrict__ tot,         // (NBUK)
                         int* __restrict__ cursor,            // (NBUK), zeroed
                         int* __restrict__ pairs) {           // (3F)
    int blk = blockIdx.x;

    if (blk < FNB) {
        int id = blk * 256 + threadIdx.x;
        if (id >= F * 8 / FQ) return;
        int b = id & 7;
        int fbase = id >> 3;                 // [0, F/FQ)

        int ia[FQ], ib[FQ], ic[FQ];
        float4 p0[FQ], p1[FQ], p2[FQ];
#pragma unroll
        for (int q = 0; q < FQ; ++q) {
            int f = fbase + q * (F / FQ);
            ia[q] = vi[f * 3 + 0];
            ib[q] = vi[f * 3 + 1];
            ic[q] = vi[f * 3 + 2];
        }
#pragma unroll
        for (int q = 0; q < FQ; ++q) {
            p0[q] = vertsT[(size_t)ia[q] * 8 + b];
            p1[q] = vertsT[(size_t)ib[q] * 8 + b];
            p2[q] = vertsT[(size_t)ic[q] * 8 + b];
        }
#pragma unroll
        for (int q = 0; q < FQ; ++q) {
            int f = fbase + q * (F / FQ);
            float e1x = p1[q].x - p0[q].x, e1y = p1[q].y - p0[q].y, e1z = p1[q].z - p0[q].z;
            float e2x = p2[q].x - p0[q].x, e2y = p2[q].y - p0[q].y, e2z = p2[q].z - p0[q].z;

            float nx = e1y * e2z - e1z * e2y;
            float ny = e1z * e2x - e1x * e2z;
            float nz = e1x * e2y - e1y * e2x;

            float norm = sqrtf(nx * nx + ny * ny + nz * nz);
            float inv = (norm < EPS) ? 1.0f : (1.0f / norm);
            fn[(size_t)f * 8 + b] = pack_h4(nx * inv, ny * inv, nz * inv);
        }
        return;
    }

    if (blk < FNB + CPB) {
        int tbase = (blk - FNB) * 256 + threadIdx.x;
        if (tbase >= T / TQ) return;
#pragma unroll
        for (int qq = 0; qq < TQ; ++qq) {
            int t = tbase + qq * (T / TQ);

            float gx = vt[t * 2 + 0];
            float gy = vt[t * 2 + 1];
            float ix = gx * (float)U - 0.5f;
            float iy = gy * (float)U - 0.5f;

            float x0f = floorf(ix);
            float y0f = floorf(iy);
            int x0 = (int)x0f;
            int y0 = (int)y0f;
            float wx1 = ix - x0f, wx0 = 1.0f - wx1;
            float wy1 = iy - y0f, wy0 = 1.0f - wy1;

#pragma unroll
            for (int c = 0; c < 4; ++c) {
                int cy = c >> 1, cx = c & 1;
                int y = y0 + cy;
                int x = x0 + cx;
                int i0 = 0, i1 = 0, i2 = 0;
                float w0 = 0.0f, w1 = 0.0f, w2 = 0.0f;
                if (x >= 0 && x < U && y >= 0 && y < U) {
                    float w = (cy ? wy1 : wy0) * (cx ? wx1 : wx0);
                    int pix = y * U + x;
                    int j0 = index_image[pix * 3 + 0];
                    int j1 = index_image[pix * 3 + 1];
                    int j2 = index_image[pix * 3 + 2];
                    float m = (j0 != -1 && j1 != -1 && j2 != -1) ? 1.0f : 0.0f;
                    float wm = w * m;
                    i0 = min(max(j0, 0), V - 1);
                    i1 = min(max(j1, 0), V - 1);
                    i2 = min(max(j2, 0), V - 1);
                    w0 = wm * bary_image[pix * 3 + 0];
                    w1 = wm * bary_image[pix * 3 + 1];
                    w2 = wm * bary_image[pix * 3 + 2];
                }
                corners[t * 4 + c] = pack_corner(i0, i1, i2, w0, w1, w2);
            }
        }
        return;
    }

    // --- scatter role: no hist matrix, no transposed scan ---
    __shared__ int pre[NBUK + 1];
    __shared__ int part[256];
    __shared__ int lh[NBUK];
    __shared__ int base[NBUK];
    scan_base(tot, pre, part);
    for (int i = threadIdx.x; i < NBUK; i += 256) lh[i] = 0;
    __syncthreads();

    int k = blk - FNB - CPB;
    int m4 = k * 256 + threadIdx.x;
    bool act = (m4 < N4);
    int vv[4], rr[4], bbk[4], fc[4];
    if (act) {
        int4 e = ((const int4*)vi)[m4];
        vv[0] = e.x; vv[1] = e.y; vv[2] = e.z; vv[3] = e.w;
        int be = m4 * 4;
#pragma unroll
        for (int j = 0; j < 4; ++j) {
            bbk[j] = vv[j] >> 7;
            rr[j] = atomicAdd(&lh[bbk[j]], 1);
            fc[j] = (be + j) / 3;
        }
    }
    __syncthreads();
    for (int i = threadIdx.x; i < NBUK; i += 256)
        base[i] = lh[i] ? atomicAdd(&cursor[i], lh[i]) : 0;
    __syncthreads();
    if (act) {
#pragma unroll
        for (int j = 0; j < 4; ++j) {
            int pos = pre[bbk[j]] + base[bbk[j]] + rr[j];
            pairs[pos] = ((vv[j] & 127) << 18) | fc[j];
        }
    }
}

// ---------------------------------------------------------------------------
// K5: per-bucket ELL build in LDS + fp16 fn gather + normalize -> fp16 vn.
// 256 threads (scan_base barrier-uniform). Gather loop unrolled x2 so two
// 64 B fn gathers are always in flight.
// ---------------------------------------------------------------------------
__global__ __launch_bounds__(256) void k5_gather(
        const int* __restrict__ pairs,
        const int* __restrict__ tot,
        const h4* __restrict__ fn,       // (F,8)
        h4* __restrict__ vn) {           // (V,8)
    __shared__ int cnt[128];
    __shared__ int rows[128 * CAP];      // 12.3 KB
    __shared__ int pre[NBUK + 1];
    __shared__ int part[256];
    scan_base(tot, pre, part);           // all 256 threads, uniform barriers

    int tid = threadIdx.x;
    if (tid < 128) cnt[tid] = 0;
    __syncthreads();

    int b = blockIdx.x;
    int start = pre[b], end = pre[b + 1];
    for (int i = start + tid; i < end; i += 256) {
        int pk = pairs[i];
        int vl = pk >> 18;
        int f = pk & 0x3FFFF;
        int pos = atomicAdd(&cnt[vl], 1);
        if (pos < CAP) rows[vl * CAP + pos] = f;
    }
    __syncthreads();

    int v0 = b << 7;
    for (int id = tid; id < 128 * 8; id += 256) {
        int vl = id >> 3, b8 = id & 7;
        int v = v0 + vl;
        if (v >= V) continue;
        int deg = min(cnt[vl], CAP);
        float ax = 0.0f, ay = 0.0f, az = 0.0f;
        int j = 0;
        for (; j + 1 < deg; j += 2) {
            h4 r0 = fn[(size_t)rows[vl * CAP + j] * 8 + b8];
            h4 r1 = fn[(size_t)rows[vl * CAP + j + 1] * 8 + b8];
            float3 n0 = unpack_h4(r0);
            float3 n1 = unpack_h4(r1);
            ax += n0.x + n1.x; ay += n0.y + n1.y; az += n0.z + n1.z;
        }
        if (j < deg) {
            float3 n = unpack_h4(fn[(size_t)rows[vl * CAP + j] * 8 + b8]);
            ax += n.x; ay += n.y; az += n.z;
        }
        float nn = sqrtf(ax * ax + ay * ay + az * az);
        float inv = (nn < EPS) ? 1.0f : (1.0f / nn);
        vn[(size_t)v * 8 + b8] = pack_h4(ax * inv, ay * inv, az * inv);
    }
}

// ---------------------------------------------------------------------------
// K6: sample with 16 B packed corners, SQ=2 samples per thread (24 vn
// gathers in flight). 8 lanes share each t -> corner loads broadcast.
// ---------------------------------------------------------------------------
__global__ void sample_points(const h4* __restrict__ vn,           // (V,8)
                              const Corner16* __restrict__ corners,// (T,4)
                              h4* __restrict__ vals) {             // (T,8)
    int id = blockIdx.x * blockDim.x + threadIdx.x;
    if (id >= (T / SQ) * 8) return;
    int b = id & 7;
    int tb = id >> 3;

#pragma unroll
    for (int s = 0; s < SQ; ++s) {
        int t = tb + s * (T / SQ);
        float ax = 0.0f, ay = 0.0f, az = 0.0f;
        Corner16 cr[4];
#pragma unroll
        for (int c = 0; c < 4; ++c) cr[c] = corners[t * 4 + c];
        h4 q[12];
#pragma unroll
        for (int c = 0; c < 4; ++c) {
            unsigned long long x = (unsigned long long)cr[c].lo
                                 | ((unsigned long long)cr[c].hi << 32);
            int i0 = (int)(x & 0x1FFFFF);
            int i1 = (int)((x >> 21) & 0x1FFFFF);
            int i2 = (int)(x >> 42);
            q[c * 3 + 0] = vn[(size_t)i0 * 8 + b];
            q[c * 3 + 1] = vn[(size_t)i1 * 8 + b];
            q[c * 3 + 2] = vn[(size_t)i2 * 8 + b];
        }
#pragma unroll
        for (int c = 0; c < 4; ++c) {
            float2 w01 = __half22float2(cr[c].w01);
            float w2 = __low2float(cr[c].w2_);
            float3 q0 = unpack_h4(q[c * 3 + 0]);
            float3 q1 = unpack_h4(q[c * 3 + 1]);
            float3 q2 = unpack_h4(q[c * 3 + 2]);
            ax += w01.x * q0.x + w01.y * q1.x + w2 * q2.x;
            ay += w01.x * q0.y + w01.y * q1.y + w2 * q2.y;
            az += w01.x * q0.z + w01.y * q1.z + w2 * q2.z;
        }
        vals[(size_t)t * 8 + b] = pack_h4(ax, ay, az);
    }
}

// ---------------------------------------------------------------------------
// K7: out[b,v,:] = mean over K=2 of vals[v2uv[v,k], b]. VQ=2 vertices per
// thread (4 gathers in flight). fp32 output.
// ---------------------------------------------------------------------------
__global__ void gather_out(const h4* __restrict__ vals,     // (T,8)
                           const int* __restrict__ v2uv,    // (V,2)
                           float* __restrict__ out) {       // (B,V,3)
    int id = blockIdx.x * blockDim.x + threadIdx.x;
    if (id >= (V / VQ) * 8) return;
    int b = id & 7;
    int vb = id >> 3;

    int t0[VQ], t1[VQ];
    h4 xa[VQ], ya[VQ];
#pragma unroll
    for (int s = 0; s < VQ; ++s) {
        int v = vb + s * (V / VQ);
        t0[s] = v2uv[v * 2 + 0];
        t1[s] = v2uv[v * 2 + 1];
    }
#pragma unroll
    for (int s = 0; s < VQ; ++s) {
        xa[s] = vals[(size_t)t0[s] * 8 + b];
        ya[s] = vals[(size_t)t1[s] * 8 + b];
    }
#pragma unroll
    for (int s = 0; s < VQ; ++s) {
        int v = vb + s * (V / VQ);
        float3 x = unpack_h4(xa[s]);
        float3 y = unpack_h4(ya[s]);
        float* o = out + (size_t)b * V * 3 + (size_t)v * 3;
        o[0] = 0.5f * (x.x + y.x);
        o[1] = 0.5f * (x.y + y.y);
        o[2] = 0.5f * (x.z + y.z);
    }
}

extern "C" void kernel_launch(void* const* d_in, const int* in_sizes, int n_in,
                              void* d_out, int out_size, void* d_ws, size_t ws_size,
                              hipStream_t stream) {
    const float* verts   = (const float*)d_in[0]; // (B,V,3)
    const float* bary    = (const float*)d_in[1]; // (U,U,3)
    const float* vt      = (const float*)d_in[2]; // (T,2)
    const int*   vi      = (const int*)d_in[3];   // (F,3)
    const int*   idx_img = (const int*)d_in[4];   // (U,U,3)
    const int*   v2uv    = (const int*)d_in[5];   // (V,2)
    float* out = (float*)d_out;

    // Workspace (~35 MB), aliased by stream-ordered disjoint lifetimes:
    //   region A (12.8 MB): vertsT float4 (K1 w, K2 r) -> vn h4 6.4 MB (K5 w, K6 r)
    //   region B (12.8 MB): fn h4 (K2 w, K5 r) -> vals h4 7.04 MB (K6 w, K7 r)
    //   region C (7.04 MB): corners 16 B packed (K2 w, K6 r)
    //   region D: tot 3 KB, cursor 3 KB, pairs 2.4 MB
    float4*   vertsT  = (float4*)d_ws;
    h4*       vn      = (h4*)d_ws;                  // alias
    h4*       fn      = (h4*)(vertsT + (size_t)V * 8);
    h4*       vals    = fn;                         // alias
    Corner16* corners = (Corner16*)((char*)fn + (size_t)F * 8 * sizeof(h4));
    int*      tot     = (int*)(corners + (size_t)T * 4);  // NBUK
    int*      cursor  = tot + NBUK;                 // NBUK
    int*      pairs   = cursor + NBUK;              // 3F

    const int BLK = 256;
    hipMemsetAsync(tot, 0, 2 * NBUK * sizeof(int), stream);     // tot + cursor
    k1_pre<<<TRB + EB, BLK, 0, stream>>>(verts, vertsT, vi, tot);
    k2_fused<<<FNB + CPB + EB, BLK, 0, stream>>>(
        vi, vertsT, fn, idx_img, bary, vt, corners, tot, cursor, pairs);
    k5_gather<<<NBUK, BLK, 0, stream>>>(pairs, tot, fn, vn);
    sample_points<<<((T / SQ) * 8 + BLK - 1) / BLK, BLK, 0, stream>>>(
        vn, corners, vals);
    gather_out<<<((V / VQ) * 8 + BLK - 1) / BLK, BLK, 0, stream>>>(
        vals, v2uv, out);
}